// Round 2
// 755.488 us; speedup vs baseline: 1.0369x; 1.0369x over previous
//
#include <hip/hip_runtime.h>

// GCN 2-layer: sigmoid( A_hat @ relu(A_hat @ (x@W1) + b1) @ W2 + b2 )
// A_hat = D^-1/2 (A + I) D^-1/2.
//
// Round 4 changes (theory: k_agg1 is gather-latency-bound + 104B rows split
// cachelines):
//  - HIDP 52 -> 64: h1 rows are exactly 128 B / 2 cachelines, always aligned.
//    Pad cols are exact zeros (Bfrag zero-padded), so agg math is unchanged.
//  - k_agg1: 8 edge-ways x 8 channel-lanes x ushort8 (16 B/lane) -> 8 edges
//    per iteration (was 4): halves the dependent-gather chain per node and
//    doubles per-instruction MLP. Way-reduce shfl_xor {8,16,32}; W2-dot
//    reduce shfl_xor {1,2,4}.
// (Round 5: resubmit unchanged — Round 1 bench died on GPUAcquisitionTimeout,
//  no measurement was taken.)

#define N_NODES 100000
#define N_EDGES 3200000
#define IN_DIM  768
#define HID     50
#define HIDP    64      // pad to full cacheline; pad cols written as 0
#define SCAN_BLK 1024
#define NSCAN_BLKS 98   // 98*1024 = 100352 >= N_NODES
#define NPAD (NSCAN_BLKS * SCAN_BLK)
#define NKSTEP (IN_DIM / 32)   // 24 k-steps of 32

using s8v = __attribute__((ext_vector_type(8))) short;           // 8 x bf16
using u8v = __attribute__((ext_vector_type(8))) unsigned short;  // 8 x bf16 bits
using f4v = __attribute__((ext_vector_type(4))) float;           // 4 x fp32

__device__ __forceinline__ short f2bf(float f) {
  union { float f; unsigned u; } v; v.f = f;
  unsigned r = (v.u + 0x7fffu + ((v.u >> 16) & 1u)) >> 16;  // RNE
  return (short)r;
}
__device__ __forceinline__ float bf2f(unsigned short u) {
  union { unsigned u; float f; } v; v.u = ((unsigned)u) << 16;
  return v.f;
}

// ---------------- degree / CSR build ----------------

__global__ void k_count(const int* __restrict__ edges, int* __restrict__ cnt,
                        int* __restrict__ pos) {
  int e = blockIdx.x * 256 + threadIdx.x;
  if (e < N_EDGES) pos[e] = atomicAdd(&cnt[edges[N_EDGES + e]], 1);
}

__global__ void k_scanA(const int* __restrict__ cnt, int* __restrict__ offs,
                        int* __restrict__ bsum) {
  __shared__ int s[SCAN_BLK];
  int t = threadIdx.x;
  int g = blockIdx.x * SCAN_BLK + t;
  int v = (g < N_NODES) ? cnt[g] : 0;
  s[t] = v;
  __syncthreads();
  for (int off = 1; off < SCAN_BLK; off <<= 1) {
    int add = (t >= off) ? s[t - off] : 0;
    __syncthreads();
    s[t] += add;
    __syncthreads();
  }
  offs[g] = s[t] - v;                    // exclusive within block
  if (t == SCAN_BLK - 1) bsum[blockIdx.x] = s[t];
}

__global__ void k_scanB(int* __restrict__ bsum) {
  __shared__ int s[128];
  int t = threadIdx.x;   // 128 threads
  int v = (t < NSCAN_BLKS) ? bsum[t] : 0;
  s[t] = v;
  __syncthreads();
  for (int off = 1; off < 128; off <<= 1) {
    int add = (t >= off) ? s[t - off] : 0;
    __syncthreads();
    s[t] += add;
    __syncthreads();
  }
  if (t < NSCAN_BLKS) bsum[t] = s[t] - v;   // exclusive
}

__global__ void k_scanC(const int* __restrict__ cnt, int* __restrict__ offs,
                        const int* __restrict__ bsum, float* __restrict__ dis) {
  int g = blockIdx.x * 256 + threadIdx.x;
  if (g < NPAD) {
    offs[g] += bsum[g >> 10];
    if (g < N_NODES)
      dis[g] = rsqrtf((float)cnt[g] + 1.0f);  // +1 = self-loop
  }
}

__global__ void k_fill(const int* __restrict__ edges, const int* __restrict__ pos,
                       const int* __restrict__ offs, int* __restrict__ eidx) {
  int e = blockIdx.x * 256 + threadIdx.x;
  if (e < N_EDGES) {
    int c = edges[N_EDGES + e];
    eidx[offs[c] + pos[e]] = edges[e];
  }
}

// ---------------- W1 -> B-fragment order ----------------
// Bfrag[((s*4+nt)*64 + lane)*8 + j] = bf16(W1[k][n]),
//   k = s*32 + (lane>>4)*8 + j, n = nt*16 + (lane&15), zero-padded n>=50.

__global__ void k_wprep(const float* __restrict__ W1, short* __restrict__ Bfrag) {
  int g = blockIdx.x * 256 + threadIdx.x;   // 24*256 = 6144
  int s = g >> 8, r = g & 255;
  int nt = r >> 6, l = r & 63;
  int col = l & 15, quad = l >> 4;
  int n = nt * 16 + col;
  int kb = s * 32 + quad * 8;
  s8v o;
#pragma unroll
  for (int j = 0; j < 8; ++j)
    o[j] = (n < HID) ? f2bf(W1[(size_t)(kb + j) * HID + n]) : (short)0;
  *(s8v*)(Bfrag + (size_t)g * 8) = o;
}

// ---------------- GEMM1: h1s = bf16((x @ W1) * dis), [N][HIDP] ----------------
// No LDS, no barriers. 4 waves/block, 32 rows/wave (2 MFMA row-tiles sharing
// B fragments), full-width (64 col) tiles.

__global__ __launch_bounds__(256) void k_gemm1(const float* __restrict__ x,
                                               const short* __restrict__ Bfrag,
                                               const float* __restrict__ dis,
                                               unsigned short* __restrict__ h1) {
  int t = threadIdx.x;
  int wave = t >> 6, lane = t & 63;
  int col = lane & 15, quad = lane >> 4;
  int rb = blockIdx.x * 128 + wave * 32;
  int arow0 = rb + col;
  int arow1 = rb + 16 + col;
  if (arow0 > N_NODES - 1) arow0 = N_NODES - 1;   // clamp; stores guarded
  if (arow1 > N_NODES - 1) arow1 = N_NODES - 1;
  const float* xrow0 = x + (size_t)arow0 * IN_DIM + quad * 8;
  const float* xrow1 = x + (size_t)arow1 * IN_DIM + quad * 8;
  const short* bbase = Bfrag + (size_t)lane * 8;

  f4v acc[8] = {f4v{0.f,0.f,0.f,0.f}, f4v{0.f,0.f,0.f,0.f},
                f4v{0.f,0.f,0.f,0.f}, f4v{0.f,0.f,0.f,0.f},
                f4v{0.f,0.f,0.f,0.f}, f4v{0.f,0.f,0.f,0.f},
                f4v{0.f,0.f,0.f,0.f}, f4v{0.f,0.f,0.f,0.f}};

#pragma unroll
  for (int s = 0; s < NKSTEP; ++s) {
    float4 va0 = *(const float4*)(xrow0 + s * 32);
    float4 vb0 = *(const float4*)(xrow0 + s * 32 + 4);
    float4 va1 = *(const float4*)(xrow1 + s * 32);
    float4 vb1 = *(const float4*)(xrow1 + s * 32 + 4);
    s8v b0 = *(const s8v*)(bbase + (size_t)(s * 4 + 0) * 512);
    s8v b1 = *(const s8v*)(bbase + (size_t)(s * 4 + 1) * 512);
    s8v b2 = *(const s8v*)(bbase + (size_t)(s * 4 + 2) * 512);
    s8v b3 = *(const s8v*)(bbase + (size_t)(s * 4 + 3) * 512);
    s8v a0, a1;
    a0[0] = f2bf(va0.x); a0[1] = f2bf(va0.y); a0[2] = f2bf(va0.z); a0[3] = f2bf(va0.w);
    a0[4] = f2bf(vb0.x); a0[5] = f2bf(vb0.y); a0[6] = f2bf(vb0.z); a0[7] = f2bf(vb0.w);
    a1[0] = f2bf(va1.x); a1[1] = f2bf(va1.y); a1[2] = f2bf(va1.z); a1[3] = f2bf(va1.w);
    a1[4] = f2bf(vb1.x); a1[5] = f2bf(vb1.y); a1[6] = f2bf(vb1.z); a1[7] = f2bf(vb1.w);
    acc[0] = __builtin_amdgcn_mfma_f32_16x16x32_bf16(a0, b0, acc[0], 0, 0, 0);
    acc[1] = __builtin_amdgcn_mfma_f32_16x16x32_bf16(a0, b1, acc[1], 0, 0, 0);
    acc[2] = __builtin_amdgcn_mfma_f32_16x16x32_bf16(a0, b2, acc[2], 0, 0, 0);
    acc[3] = __builtin_amdgcn_mfma_f32_16x16x32_bf16(a0, b3, acc[3], 0, 0, 0);
    acc[4] = __builtin_amdgcn_mfma_f32_16x16x32_bf16(a1, b0, acc[4], 0, 0, 0);
    acc[5] = __builtin_amdgcn_mfma_f32_16x16x32_bf16(a1, b1, acc[5], 0, 0, 0);
    acc[6] = __builtin_amdgcn_mfma_f32_16x16x32_bf16(a1, b2, acc[6], 0, 0, 0);
    acc[7] = __builtin_amdgcn_mfma_f32_16x16x32_bf16(a1, b3, acc[7], 0, 0, 0);
  }

  // C/D layout: col = lane&15, row = quad*4 + reg  [m89/m91]
#pragma unroll
  for (int half = 0; half < 2; ++half) {
    int node0 = rb + half * 16 + quad * 4;
    float dd[4];
#pragma unroll
    for (int r = 0; r < 4; ++r)
      dd[r] = (node0 + r < N_NODES) ? dis[node0 + r] : 0.f;
#pragma unroll
    for (int nt = 0; nt < 4; ++nt) {
      int c = nt * 16 + col;
#pragma unroll
      for (int r = 0; r < 4; ++r) {
        int node = node0 + r;
        if (node < N_NODES)
          h1[(size_t)node * HIDP + c] =
              (unsigned short)f2bf(acc[half * 4 + nt][r] * dd[r]);
      }
    }
  }
}

// ---------------- layer-1 aggregate + bias + relu + GEMM2 ----------------
// 1 wave per node: 8 edge-ways x 8 channel-lanes (8 ch each, ushort8 = 16 B).
// h1 rows are pre-scaled by dis => plain gather-sum, no per-edge dis.
// Each gather = one aligned 128-B row = exactly 2 cachelines.

__global__ __launch_bounds__(256) void k_agg1(
    const unsigned short* __restrict__ h1, const int* __restrict__ eidx,
    const int* __restrict__ offs, const float* __restrict__ dis,
    const float* __restrict__ b1, const float* __restrict__ W2,
    float* __restrict__ h2s) {
  __shared__ float W2s[2][64];
  __shared__ float b1s[64];
  int t = threadIdx.x;
  if (t < 64) {
    b1s[t] = (t < HID) ? b1[t] : 0.f;
    W2s[0][t] = (t < HID) ? W2[t * 2 + 0] : 0.f;
    W2s[1][t] = (t < HID) ? W2[t * 2 + 1] : 0.f;
  }
  __syncthreads();
  int wave = t >> 6, lane = t & 63;
  int n = blockIdx.x * 4 + wave;
  if (n >= N_NODES) return;
  int way = lane >> 3;       // 8 edge-ways
  int L = lane & 7;          // 8 channel lanes, 8 ch each
  int base = L * 8;
  int start = offs[n];
  int end = (n == N_NODES - 1) ? N_EDGES : offs[n + 1];

  float a[8] = {0.f, 0.f, 0.f, 0.f, 0.f, 0.f, 0.f, 0.f};
  // depth-2 software pipeline: prefetch eidx and h1-gather one iter ahead
  int i  = start + way;
  int idx  = (i  < end) ? eidx[i]  : n;
  u8v u = *(const u8v*)(h1 + (size_t)idx * HIDP + base);
  int i2 = i + 8;
  int idx2 = (i2 < end) ? eidx[i2] : n;
  while (i < end) {
    u8v u2 = *(const u8v*)(h1 + (size_t)idx2 * HIDP + base);
    int i3 = i2 + 8;
    int idx3 = (i3 < end) ? eidx[i3] : n;
#pragma unroll
    for (int j = 0; j < 8; ++j) a[j] += bf2f(u[j]);
    u = u2; idx2 = idx3; i = i2; i2 = i3;
  }

  // reduce across the 8 edge-ways (all lanes participate)
#pragma unroll
  for (int j = 0; j < 8; ++j) {
    a[j] += __shfl_xor(a[j], 8);
    a[j] += __shfl_xor(a[j], 16);
    a[j] += __shfl_xor(a[j], 32);
  }

  float p0 = 0.f, p1 = 0.f;
  if (way == 0) {
    float dn = dis[n];
    u8v us = *(const u8v*)(h1 + (size_t)n * HIDP + base);  // self (pre-scaled)
#pragma unroll
    for (int j = 0; j < 8; ++j) {
      float s = (a[j] + bf2f(us[j])) * dn + b1s[base + j];
      s = fmaxf(s, 0.f);
      p0 += s * W2s[0][base + j];
      p1 += s * W2s[1][base + j];
    }
  }
  // reduce across the 8 channel lanes (xor 1,2,4 stays within way 0's group;
  // other ways contribute 0)
  p0 += __shfl_xor(p0, 1); p0 += __shfl_xor(p0, 2); p0 += __shfl_xor(p0, 4);
  p1 += __shfl_xor(p1, 1); p1 += __shfl_xor(p1, 2); p1 += __shfl_xor(p1, 4);
  if (lane == 0) {
    float dn = dis[n];
    h2s[(size_t)n * 2 + 0] = p0 * dn;   // pre-scale for layer 2
    h2s[(size_t)n * 2 + 1] = p1 * dn;
  }
}

// ---------------- layer-2 aggregate + bias + sigmoid ----------------
// 1 wave per node, 64-way edge stride (deg~33 -> typically 1 gather round).

__global__ __launch_bounds__(256) void k_agg2(
    const float* __restrict__ h2s, const int* __restrict__ eidx,
    const int* __restrict__ offs, const float* __restrict__ dis,
    const float* __restrict__ b2, float* __restrict__ out) {
  int t = threadIdx.x;
  int wave = t >> 6, lane = t & 63;
  int n = blockIdx.x * 4 + wave;
  if (n >= N_NODES) return;
  int start = offs[n];
  int end = (n == N_NODES - 1) ? N_EDGES : offs[n + 1];
  float s0 = 0.f, s1 = 0.f;
  for (int i = start + lane; i < end; i += 64) {
    int idx = eidx[i];
    float2 v = *(const float2*)(h2s + (size_t)idx * 2);
    s0 += v.x; s1 += v.y;
  }
  for (int m = 32; m; m >>= 1) {
    s0 += __shfl_xor(s0, m);
    s1 += __shfl_xor(s1, m);
  }
  if (lane == 0) {
    float dn = dis[n];
    float2 v = *(const float2*)(h2s + (size_t)n * 2);
    float r0 = (s0 + v.x) * dn + b2[0];
    float r1 = (s1 + v.y) * dn + b2[1];
    out[(size_t)n * 2 + 0] = 1.f / (1.f + __expf(-r0));
    out[(size_t)n * 2 + 1] = 1.f / (1.f + __expf(-r1));
  }
}

// ---------------- launch ----------------

static inline size_t aln(size_t v) { return (v + 255) & ~(size_t)255; }

extern "C" void kernel_launch(void* const* d_in, const int* in_sizes, int n_in,
                              void* d_out, int out_size, void* d_ws, size_t ws_size,
                              hipStream_t stream) {
  const float* x     = (const float*)d_in[0];
  const int*   edges = (const int*)d_in[1];     // [2][E]: rows then cols
  const float* W1    = (const float*)d_in[2];   // [768][50]
  const float* b1    = (const float*)d_in[3];
  const float* W2    = (const float*)d_in[4];   // [50][2]
  const float* b2    = (const float*)d_in[5];
  float* out = (float*)d_out;

  char* p = (char*)d_ws;
  int* cnt  = (int*)p;            p += aln((size_t)NPAD * 4);
  int* offs = (int*)p;            p += aln((size_t)NPAD * 4);
  int* bsum = (int*)p;            p += aln((size_t)NSCAN_BLKS * 4);
  float* dis = (float*)p;         p += aln((size_t)N_NODES * 4);
  int* eidx = (int*)p;            p += aln((size_t)N_EDGES * 4);
  int* pos  = (int*)p;            p += aln((size_t)N_EDGES * 4);
  short* Bfrag = (short*)p;       p += aln((size_t)NKSTEP * 4 * 64 * 8 * 2);
  unsigned short* h1 = (unsigned short*)p; p += aln((size_t)N_NODES * HIDP * 2);
  float* h2s = (float*)p;         p += aln((size_t)N_NODES * 2 * 4);

  int gN   = (NPAD + 255) / 256;            // 392
  int gE   = (N_EDGES + 255) / 256;         // 12500
  int gMM  = (N_NODES + 127) / 128;         // 782
  int gW   = (N_NODES + 3) / 4;             // 25000 (wave per node)

  hipMemsetAsync(cnt, 0, (size_t)N_NODES * 4, stream);
  k_count<<<gE, 256, 0, stream>>>(edges, cnt, pos);
  k_scanA<<<NSCAN_BLKS, SCAN_BLK, 0, stream>>>(cnt, offs, bsum);
  k_scanB<<<1, 128, 0, stream>>>(bsum);
  k_scanC<<<gN, 256, 0, stream>>>(cnt, offs, bsum, dis);
  k_fill <<<gE, 256, 0, stream>>>(edges, pos, offs, eidx);
  k_wprep<<<NKSTEP, 256, 0, stream>>>(W1, Bfrag);
  k_gemm1<<<gMM, 256, 0, stream>>>(x, Bfrag, dis, h1);
  k_agg1 <<<gW, 256, 0, stream>>>(h1, eidx, offs, dis, b1, W2, h2s);
  k_agg2 <<<gW, 256, 0, stream>>>(h2s, eidx, offs, dis, b2, out);
}

// Round 3
// 755.486 us; speedup vs baseline: 1.0369x; 1.0000x over previous
//
#include <hip/hip_runtime.h>

// GCN 2-layer: sigmoid( A_hat @ relu(A_hat @ (x@W1) + b1) @ W2 + b2 )
// A_hat = D^-1/2 (A + I) D^-1/2.
//
// Round 6 change (single hypothesis: k_agg1 is gather-LATENCY-bound, 1
// outstanding gather/wave):
//  - k_agg1 inner loop -> 4-wide batched gathers: 4 eidx loads + 4 h1
//    gathers issued back-to-back per round (32 edges in flight/wave, 4x MLP).
//    Typical node (deg<=32) = ONE exposed eidx->gather chain instead of 4
//    serialized rounds. Out-of-range slots gather safe row h1[n] (L1-hot)
//    and are masked out of the accumulate with cndmask.
//  - Everything else unchanged (clean A/B on the agg1 edit).

#define N_NODES 100000
#define N_EDGES 3200000
#define IN_DIM  768
#define HID     50
#define HIDP    64      // pad to full cacheline; pad cols written as 0
#define SCAN_BLK 1024
#define NSCAN_BLKS 98   // 98*1024 = 100352 >= N_NODES
#define NPAD (NSCAN_BLKS * SCAN_BLK)
#define NKSTEP (IN_DIM / 32)   // 24 k-steps of 32

using s8v = __attribute__((ext_vector_type(8))) short;           // 8 x bf16
using u8v = __attribute__((ext_vector_type(8))) unsigned short;  // 8 x bf16 bits
using f4v = __attribute__((ext_vector_type(4))) float;           // 4 x fp32

__device__ __forceinline__ short f2bf(float f) {
  union { float f; unsigned u; } v; v.f = f;
  unsigned r = (v.u + 0x7fffu + ((v.u >> 16) & 1u)) >> 16;  // RNE
  return (short)r;
}
__device__ __forceinline__ float bf2f(unsigned short u) {
  union { unsigned u; float f; } v; v.u = ((unsigned)u) << 16;
  return v.f;
}

// ---------------- degree / CSR build ----------------

__global__ void k_count(const int* __restrict__ edges, int* __restrict__ cnt,
                        int* __restrict__ pos) {
  int e = blockIdx.x * 256 + threadIdx.x;
  if (e < N_EDGES) pos[e] = atomicAdd(&cnt[edges[N_EDGES + e]], 1);
}

__global__ void k_scanA(const int* __restrict__ cnt, int* __restrict__ offs,
                        int* __restrict__ bsum) {
  __shared__ int s[SCAN_BLK];
  int t = threadIdx.x;
  int g = blockIdx.x * SCAN_BLK + t;
  int v = (g < N_NODES) ? cnt[g] : 0;
  s[t] = v;
  __syncthreads();
  for (int off = 1; off < SCAN_BLK; off <<= 1) {
    int add = (t >= off) ? s[t - off] : 0;
    __syncthreads();
    s[t] += add;
    __syncthreads();
  }
  offs[g] = s[t] - v;                    // exclusive within block
  if (t == SCAN_BLK - 1) bsum[blockIdx.x] = s[t];
}

__global__ void k_scanB(int* __restrict__ bsum) {
  __shared__ int s[128];
  int t = threadIdx.x;   // 128 threads
  int v = (t < NSCAN_BLKS) ? bsum[t] : 0;
  s[t] = v;
  __syncthreads();
  for (int off = 1; off < 128; off <<= 1) {
    int add = (t >= off) ? s[t - off] : 0;
    __syncthreads();
    s[t] += add;
    __syncthreads();
  }
  if (t < NSCAN_BLKS) bsum[t] = s[t] - v;   // exclusive
}

__global__ void k_scanC(const int* __restrict__ cnt, int* __restrict__ offs,
                        const int* __restrict__ bsum, float* __restrict__ dis) {
  int g = blockIdx.x * 256 + threadIdx.x;
  if (g < NPAD) {
    offs[g] += bsum[g >> 10];
    if (g < N_NODES)
      dis[g] = rsqrtf((float)cnt[g] + 1.0f);  // +1 = self-loop
  }
}

__global__ void k_fill(const int* __restrict__ edges, const int* __restrict__ pos,
                       const int* __restrict__ offs, int* __restrict__ eidx) {
  int e = blockIdx.x * 256 + threadIdx.x;
  if (e < N_EDGES) {
    int c = edges[N_EDGES + e];
    eidx[offs[c] + pos[e]] = edges[e];
  }
}

// ---------------- W1 -> B-fragment order ----------------
// Bfrag[((s*4+nt)*64 + lane)*8 + j] = bf16(W1[k][n]),
//   k = s*32 + (lane>>4)*8 + j, n = nt*16 + (lane&15), zero-padded n>=50.

__global__ void k_wprep(const float* __restrict__ W1, short* __restrict__ Bfrag) {
  int g = blockIdx.x * 256 + threadIdx.x;   // 24*256 = 6144
  int s = g >> 8, r = g & 255;
  int nt = r >> 6, l = r & 63;
  int col = l & 15, quad = l >> 4;
  int n = nt * 16 + col;
  int kb = s * 32 + quad * 8;
  s8v o;
#pragma unroll
  for (int j = 0; j < 8; ++j)
    o[j] = (n < HID) ? f2bf(W1[(size_t)(kb + j) * HID + n]) : (short)0;
  *(s8v*)(Bfrag + (size_t)g * 8) = o;
}

// ---------------- GEMM1: h1s = bf16((x @ W1) * dis), [N][HIDP] ----------------
// No LDS, no barriers. 4 waves/block, 32 rows/wave (2 MFMA row-tiles sharing
// B fragments), full-width (64 col) tiles.

__global__ __launch_bounds__(256) void k_gemm1(const float* __restrict__ x,
                                               const short* __restrict__ Bfrag,
                                               const float* __restrict__ dis,
                                               unsigned short* __restrict__ h1) {
  int t = threadIdx.x;
  int wave = t >> 6, lane = t & 63;
  int col = lane & 15, quad = lane >> 4;
  int rb = blockIdx.x * 128 + wave * 32;
  int arow0 = rb + col;
  int arow1 = rb + 16 + col;
  if (arow0 > N_NODES - 1) arow0 = N_NODES - 1;   // clamp; stores guarded
  if (arow1 > N_NODES - 1) arow1 = N_NODES - 1;
  const float* xrow0 = x + (size_t)arow0 * IN_DIM + quad * 8;
  const float* xrow1 = x + (size_t)arow1 * IN_DIM + quad * 8;
  const short* bbase = Bfrag + (size_t)lane * 8;

  f4v acc[8] = {f4v{0.f,0.f,0.f,0.f}, f4v{0.f,0.f,0.f,0.f},
                f4v{0.f,0.f,0.f,0.f}, f4v{0.f,0.f,0.f,0.f},
                f4v{0.f,0.f,0.f,0.f}, f4v{0.f,0.f,0.f,0.f},
                f4v{0.f,0.f,0.f,0.f}, f4v{0.f,0.f,0.f,0.f}};

#pragma unroll
  for (int s = 0; s < NKSTEP; ++s) {
    float4 va0 = *(const float4*)(xrow0 + s * 32);
    float4 vb0 = *(const float4*)(xrow0 + s * 32 + 4);
    float4 va1 = *(const float4*)(xrow1 + s * 32);
    float4 vb1 = *(const float4*)(xrow1 + s * 32 + 4);
    s8v b0 = *(const s8v*)(bbase + (size_t)(s * 4 + 0) * 512);
    s8v b1 = *(const s8v*)(bbase + (size_t)(s * 4 + 1) * 512);
    s8v b2 = *(const s8v*)(bbase + (size_t)(s * 4 + 2) * 512);
    s8v b3 = *(const s8v*)(bbase + (size_t)(s * 4 + 3) * 512);
    s8v a0, a1;
    a0[0] = f2bf(va0.x); a0[1] = f2bf(va0.y); a0[2] = f2bf(va0.z); a0[3] = f2bf(va0.w);
    a0[4] = f2bf(vb0.x); a0[5] = f2bf(vb0.y); a0[6] = f2bf(vb0.z); a0[7] = f2bf(vb0.w);
    a1[0] = f2bf(va1.x); a1[1] = f2bf(va1.y); a1[2] = f2bf(va1.z); a1[3] = f2bf(va1.w);
    a1[4] = f2bf(vb1.x); a1[5] = f2bf(vb1.y); a1[6] = f2bf(vb1.z); a1[7] = f2bf(vb1.w);
    acc[0] = __builtin_amdgcn_mfma_f32_16x16x32_bf16(a0, b0, acc[0], 0, 0, 0);
    acc[1] = __builtin_amdgcn_mfma_f32_16x16x32_bf16(a0, b1, acc[1], 0, 0, 0);
    acc[2] = __builtin_amdgcn_mfma_f32_16x16x32_bf16(a0, b2, acc[2], 0, 0, 0);
    acc[3] = __builtin_amdgcn_mfma_f32_16x16x32_bf16(a0, b3, acc[3], 0, 0, 0);
    acc[4] = __builtin_amdgcn_mfma_f32_16x16x32_bf16(a1, b0, acc[4], 0, 0, 0);
    acc[5] = __builtin_amdgcn_mfma_f32_16x16x32_bf16(a1, b1, acc[5], 0, 0, 0);
    acc[6] = __builtin_amdgcn_mfma_f32_16x16x32_bf16(a1, b2, acc[6], 0, 0, 0);
    acc[7] = __builtin_amdgcn_mfma_f32_16x16x32_bf16(a1, b3, acc[7], 0, 0, 0);
  }

  // C/D layout: col = lane&15, row = quad*4 + reg  [m89/m91]
#pragma unroll
  for (int half = 0; half < 2; ++half) {
    int node0 = rb + half * 16 + quad * 4;
    float dd[4];
#pragma unroll
    for (int r = 0; r < 4; ++r)
      dd[r] = (node0 + r < N_NODES) ? dis[node0 + r] : 0.f;
#pragma unroll
    for (int nt = 0; nt < 4; ++nt) {
      int c = nt * 16 + col;
#pragma unroll
      for (int r = 0; r < 4; ++r) {
        int node = node0 + r;
        if (node < N_NODES)
          h1[(size_t)node * HIDP + c] =
              (unsigned short)f2bf(acc[half * 4 + nt][r] * dd[r]);
      }
    }
  }
}

// ---------------- layer-1 aggregate + bias + relu + GEMM2 ----------------
// 1 wave per node: 8 edge-ways x 8 channel-lanes (8 ch each, ushort8 = 16 B).
// h1 rows are pre-scaled by dis => plain gather-sum, no per-edge dis.
// 4-wide batched gather: 32 edges in flight per wave per round.

__global__ __launch_bounds__(256) void k_agg1(
    const unsigned short* __restrict__ h1, const int* __restrict__ eidx,
    const int* __restrict__ offs, const float* __restrict__ dis,
    const float* __restrict__ b1, const float* __restrict__ W2,
    float* __restrict__ h2s) {
  __shared__ float W2s[2][64];
  __shared__ float b1s[64];
  int t = threadIdx.x;
  if (t < 64) {
    b1s[t] = (t < HID) ? b1[t] : 0.f;
    W2s[0][t] = (t < HID) ? W2[t * 2 + 0] : 0.f;
    W2s[1][t] = (t < HID) ? W2[t * 2 + 1] : 0.f;
  }
  __syncthreads();
  int wave = t >> 6, lane = t & 63;
  int n = blockIdx.x * 4 + wave;
  if (n >= N_NODES) return;
  int way = lane >> 3;       // 8 edge-ways
  int L = lane & 7;          // 8 channel lanes, 8 ch each
  int base = L * 8;
  int start = offs[n];
  int end = (n == N_NODES - 1) ? N_EDGES : offs[n + 1];

  float a[8] = {0.f, 0.f, 0.f, 0.f, 0.f, 0.f, 0.f, 0.f};
  // 4-wide batched gather rounds: slots i, i+8, i+16, i+24 issued together.
  // Typical node (deg <= 32) finishes in one round = one exposed
  // eidx->gather latency chain (was 4 serialized rounds).
#pragma unroll 1
  for (int ib = start + way; ib < end; ib += 32) {
    int iB = ib + 8, iC = ib + 16, iD = ib + 24;
    int idxA = eidx[ib];                       // ib < end guaranteed
    int idxB = (iB < end) ? eidx[iB] : n;      // safe row, masked below
    int idxC = (iC < end) ? eidx[iC] : n;
    int idxD = (iD < end) ? eidx[iD] : n;
    u8v uA = *(const u8v*)(h1 + (size_t)idxA * HIDP + base);
    u8v uB = *(const u8v*)(h1 + (size_t)idxB * HIDP + base);
    u8v uC = *(const u8v*)(h1 + (size_t)idxC * HIDP + base);
    u8v uD = *(const u8v*)(h1 + (size_t)idxD * HIDP + base);
    bool vB = iB < end, vC = iC < end, vD = iD < end;
#pragma unroll
    for (int j = 0; j < 8; ++j) {
      a[j] += bf2f(uA[j]);
      a[j] += vB ? bf2f(uB[j]) : 0.f;
      a[j] += vC ? bf2f(uC[j]) : 0.f;
      a[j] += vD ? bf2f(uD[j]) : 0.f;
    }
  }

  // reduce across the 8 edge-ways (all lanes participate)
#pragma unroll
  for (int j = 0; j < 8; ++j) {
    a[j] += __shfl_xor(a[j], 8);
    a[j] += __shfl_xor(a[j], 16);
    a[j] += __shfl_xor(a[j], 32);
  }

  float p0 = 0.f, p1 = 0.f;
  if (way == 0) {
    float dn = dis[n];
    u8v us = *(const u8v*)(h1 + (size_t)n * HIDP + base);  // self (pre-scaled)
#pragma unroll
    for (int j = 0; j < 8; ++j) {
      float s = (a[j] + bf2f(us[j])) * dn + b1s[base + j];
      s = fmaxf(s, 0.f);
      p0 += s * W2s[0][base + j];
      p1 += s * W2s[1][base + j];
    }
  }
  // reduce across the 8 channel lanes (xor 1,2,4 stays within way 0's group;
  // other ways contribute 0)
  p0 += __shfl_xor(p0, 1); p0 += __shfl_xor(p0, 2); p0 += __shfl_xor(p0, 4);
  p1 += __shfl_xor(p1, 1); p1 += __shfl_xor(p1, 2); p1 += __shfl_xor(p1, 4);
  if (lane == 0) {
    float dn = dis[n];
    h2s[(size_t)n * 2 + 0] = p0 * dn;   // pre-scale for layer 2
    h2s[(size_t)n * 2 + 1] = p1 * dn;
  }
}

// ---------------- layer-2 aggregate + bias + sigmoid ----------------
// 1 wave per node, 64-way edge stride (deg~33 -> typically 1 gather round).

__global__ __launch_bounds__(256) void k_agg2(
    const float* __restrict__ h2s, const int* __restrict__ eidx,
    const int* __restrict__ offs, const float* __restrict__ dis,
    const float* __restrict__ b2, float* __restrict__ out) {
  int t = threadIdx.x;
  int wave = t >> 6, lane = t & 63;
  int n = blockIdx.x * 4 + wave;
  if (n >= N_NODES) return;
  int start = offs[n];
  int end = (n == N_NODES - 1) ? N_EDGES : offs[n + 1];
  float s0 = 0.f, s1 = 0.f;
  for (int i = start + lane; i < end; i += 64) {
    int idx = eidx[i];
    float2 v = *(const float2*)(h2s + (size_t)idx * 2);
    s0 += v.x; s1 += v.y;
  }
  for (int m = 32; m; m >>= 1) {
    s0 += __shfl_xor(s0, m);
    s1 += __shfl_xor(s1, m);
  }
  if (lane == 0) {
    float dn = dis[n];
    float2 v = *(const float2*)(h2s + (size_t)n * 2);
    float r0 = (s0 + v.x) * dn + b2[0];
    float r1 = (s1 + v.y) * dn + b2[1];
    out[(size_t)n * 2 + 0] = 1.f / (1.f + __expf(-r0));
    out[(size_t)n * 2 + 1] = 1.f / (1.f + __expf(-r1));
  }
}

// ---------------- launch ----------------

static inline size_t aln(size_t v) { return (v + 255) & ~(size_t)255; }

extern "C" void kernel_launch(void* const* d_in, const int* in_sizes, int n_in,
                              void* d_out, int out_size, void* d_ws, size_t ws_size,
                              hipStream_t stream) {
  const float* x     = (const float*)d_in[0];
  const int*   edges = (const int*)d_in[1];     // [2][E]: rows then cols
  const float* W1    = (const float*)d_in[2];   // [768][50]
  const float* b1    = (const float*)d_in[3];
  const float* W2    = (const float*)d_in[4];   // [50][2]
  const float* b2    = (const float*)d_in[5];
  float* out = (float*)d_out;

  char* p = (char*)d_ws;
  int* cnt  = (int*)p;            p += aln((size_t)NPAD * 4);
  int* offs = (int*)p;            p += aln((size_t)NPAD * 4);
  int* bsum = (int*)p;            p += aln((size_t)NSCAN_BLKS * 4);
  float* dis = (float*)p;         p += aln((size_t)N_NODES * 4);
  int* eidx = (int*)p;            p += aln((size_t)N_EDGES * 4);
  int* pos  = (int*)p;            p += aln((size_t)N_EDGES * 4);
  short* Bfrag = (short*)p;       p += aln((size_t)NKSTEP * 4 * 64 * 8 * 2);
  unsigned short* h1 = (unsigned short*)p; p += aln((size_t)N_NODES * HIDP * 2);
  float* h2s = (float*)p;         p += aln((size_t)N_NODES * 2 * 4);

  int gN   = (NPAD + 255) / 256;            // 392
  int gE   = (N_EDGES + 255) / 256;         // 12500
  int gMM  = (N_NODES + 127) / 128;         // 782
  int gW   = (N_NODES + 3) / 4;             // 25000 (wave per node)

  hipMemsetAsync(cnt, 0, (size_t)N_NODES * 4, stream);
  k_count<<<gE, 256, 0, stream>>>(edges, cnt, pos);
  k_scanA<<<NSCAN_BLKS, SCAN_BLK, 0, stream>>>(cnt, offs, bsum);
  k_scanB<<<1, 128, 0, stream>>>(bsum);
  k_scanC<<<gN, 256, 0, stream>>>(cnt, offs, bsum, dis);
  k_fill <<<gE, 256, 0, stream>>>(edges, pos, offs, eidx);
  k_wprep<<<NKSTEP, 256, 0, stream>>>(W1, Bfrag);
  k_gemm1<<<gMM, 256, 0, stream>>>(x, Bfrag, dis, h1);
  k_agg1 <<<gW, 256, 0, stream>>>(h1, eidx, offs, dis, b1, W2, h2s);
  k_agg2 <<<gW, 256, 0, stream>>>(h2s, eidx, offs, dis, b2, out);
}